// Round 1
// baseline (3081.244 us; speedup 1.0000x reference)
//
#include <hip/hip_runtime.h>
#include <cstddef>

#define BATCH 8
#define H_ 64
#define W_ 64
#define HW (H_*W_)
#define DIM 256
#define HEADS 8
#define KK 9

constexpr float kEps = 1e-5f;
constexpr float kInvSqrtD = 0.17677669529663687f;  // 32^-0.5

// ---------------------------------------------------------------------------
// conv3x3 (pad=1) + BN (inference affine) + ReLU, direct fp32.
// One thread computes OPT output channels for one pixel.
// Weight addresses are wave-uniform -> scalar loads.
// ---------------------------------------------------------------------------
template<int C_IN, int OPT>
__global__ __launch_bounds__(256) void conv3x3_bn_relu(
    const float* __restrict__ in, const float* __restrict__ w,
    const float* __restrict__ g, const float* __restrict__ bbias,
    const float* __restrict__ bm, const float* __restrict__ bv,
    float* __restrict__ out, int C_out)
{
    const int tid = threadIdx.x;
    const int p   = blockIdx.x * 256 + tid;   // pixel over B*H*W
    const int b   = p >> 12;                  // /4096
    const int yx  = p & 4095;
    const int y   = yx >> 6;
    const int x   = yx & 63;
    const int o0  = blockIdx.y * OPT;

    float acc[OPT];
    #pragma unroll
    for (int o = 0; o < OPT; ++o) acc[o] = 0.f;

    const float* ip0 = in + (size_t)b * C_IN * HW + yx;
    const float* wp0 = w + (size_t)o0 * C_IN * 9;

    const bool ym = (y > 0), yp = (y < H_ - 1);
    const bool xm = (x > 0), xp = (x < W_ - 1);

    for (int c = 0; c < C_IN; ++c) {
        const float* ip = ip0 + c * HW;
        float xv[9];
        xv[0] = (ym && xm) ? ip[-W_ - 1] : 0.f;
        xv[1] = (ym)       ? ip[-W_]     : 0.f;
        xv[2] = (ym && xp) ? ip[-W_ + 1] : 0.f;
        xv[3] = (xm)       ? ip[-1]      : 0.f;
        xv[4] =              ip[0];
        xv[5] = (xp)       ? ip[1]       : 0.f;
        xv[6] = (yp && xm) ? ip[W_ - 1]  : 0.f;
        xv[7] = (yp)       ? ip[W_]      : 0.f;
        xv[8] = (yp && xp) ? ip[W_ + 1]  : 0.f;

        const float* wp = wp0 + c * 9;
        #pragma unroll
        for (int o = 0; o < OPT; ++o) {
            const float* wo = wp + (size_t)o * C_IN * 9;
            #pragma unroll
            for (int t = 0; t < 9; ++t)
                acc[o] = fmaf(xv[t], wo[t], acc[o]);
        }
    }

    #pragma unroll
    for (int o = 0; o < OPT; ++o) {
        const int oc = o0 + o;
        const float sc = g[oc] * rsqrtf(bv[oc] + kEps);
        const float sh = bbias[oc] - bm[oc] * sc;
        float r = fmaxf(fmaf(acc[o], sc, sh), 0.f);
        out[((size_t)b * C_out + oc) * HW + yx] = r;
    }
}

// ---------------------------------------------------------------------------
// 1x1 conv: out[b,o,yx] = sum_c W[o,c] * in[b,c,yx] (* S[b,c/32,yx] opt) + bias
// ---------------------------------------------------------------------------
template<int C_IN, int OPT, bool WITH_S>
__global__ __launch_bounds__(256) void conv1x1_kernel(
    const float* __restrict__ in, const float* __restrict__ W,
    const float* __restrict__ bias, const float* __restrict__ Smap,
    float* __restrict__ out, int C_out)
{
    const int tid = threadIdx.x;
    const int p   = blockIdx.x * 256 + tid;
    const int b   = p >> 12;
    const int yx  = p & 4095;
    const int o0  = blockIdx.y * OPT;

    float acc[OPT];
    #pragma unroll
    for (int o = 0; o < OPT; ++o) acc[o] = 0.f;

    const float* ip0 = in + (size_t)b * C_IN * HW + yx;

    for (int cg = 0; cg < C_IN / 32; ++cg) {
        float s = 1.f;
        if (WITH_S) s = Smap[((size_t)b * HEADS + cg) * HW + yx];
        #pragma unroll 8
        for (int ci = 0; ci < 32; ++ci) {
            const int c = cg * 32 + ci;
            float v = ip0[(size_t)c * HW];
            if (WITH_S) v *= s;
            const float* wp = W + (size_t)o0 * C_IN + c;
            #pragma unroll
            for (int o = 0; o < OPT; ++o)
                acc[o] = fmaf(v, wp[(size_t)o * C_IN], acc[o]);
        }
    }

    #pragma unroll
    for (int o = 0; o < OPT; ++o) {
        const int oc = o0 + o;
        out[((size_t)b * C_out + oc) * HW + yx] = acc[o] + bias[oc];
    }
}

// ---------------------------------------------------------------------------
// attention logits + softmax: per pixel compute 72 logits
//   d[o] = sum_c (Wfg[o,c]*fg - Wbg[o,c]*bg) + (bfg[o]-bbg[o])
// then per-head (groups of 9) softmax of d*D^-0.5; store attn[b,h,kk,y,x].
// ---------------------------------------------------------------------------
__global__ __launch_bounds__(256) void attn_kernel(
    const float* __restrict__ fg, const float* __restrict__ bg,
    const float* __restrict__ Wfg, const float* __restrict__ bfg,
    const float* __restrict__ Wbg, const float* __restrict__ bbg,
    float* __restrict__ attn)
{
    const int p  = blockIdx.x * 256 + threadIdx.x;
    const int b  = p >> 12;
    const int yx = p & 4095;

    float d[72];
    #pragma unroll
    for (int o = 0; o < 72; ++o) d[o] = bfg[o] - bbg[o];

    const float* fp = fg + (size_t)b * DIM * HW + yx;
    const float* gp = bg + (size_t)b * DIM * HW + yx;

    for (int c = 0; c < DIM; ++c) {
        const float fv = fp[(size_t)c * HW];
        const float gv = gp[(size_t)c * HW];
        #pragma unroll
        for (int o = 0; o < 72; ++o) {
            d[o] = fmaf(Wfg[(size_t)o * DIM + c], fv, d[o]);
            d[o] = fmaf(-Wbg[(size_t)o * DIM + c], gv, d[o]);
        }
    }

    #pragma unroll
    for (int h = 0; h < HEADS; ++h) {
        float l[KK];
        #pragma unroll
        for (int k = 0; k < KK; ++k) l[k] = d[h * KK + k] * kInvSqrtD;
        float mx = l[0];
        #pragma unroll
        for (int k = 1; k < KK; ++k) mx = fmaxf(mx, l[k]);
        float e[KK], sum = 0.f;
        #pragma unroll
        for (int k = 0; k < KK; ++k) { e[k] = __expf(l[k] - mx); sum += e[k]; }
        const float inv = 1.f / sum;
        #pragma unroll
        for (int k = 0; k < KK; ++k)
            attn[(((size_t)b * HEADS + h) * KK + k) * HW + yx] = e[k] * inv;
    }
}

// ---------------------------------------------------------------------------
// S[b,h,y,x] = sum over (i,j) of attn[b,h,i*3+j, y+1-i, x+1-j] (valid range)
// (the fold/col2im collapses to this neighborhood sum)
// ---------------------------------------------------------------------------
__global__ __launch_bounds__(256) void fold_sum_kernel(
    const float* __restrict__ attn, float* __restrict__ S)
{
    const int idx = blockIdx.x * 256 + threadIdx.x;  // over B*HEADS*HW
    const int bh  = idx >> 12;
    const int yx  = idx & 4095;
    const int y   = yx >> 6;
    const int x   = yx & 63;

    const float* ap = attn + (size_t)bh * KK * HW;
    float s = 0.f;
    #pragma unroll
    for (int i = 0; i < 3; ++i) {
        const int ys = y + 1 - i;
        if (ys < 0 || ys >= H_) continue;
        #pragma unroll
        for (int j = 0; j < 3; ++j) {
            const int xs = x + 1 - j;
            if (xs < 0 || xs >= W_) continue;
            s += ap[(size_t)(i * 3 + j) * HW + ys * W_ + xs];
        }
    }
    S[idx] = s;
}

// ---------------------------------------------------------------------------
extern "C" void kernel_launch(void* const* d_in, const int* in_sizes, int n_in,
                              void* d_out, int out_size, void* d_ws, size_t ws_size,
                              hipStream_t stream)
{
    const float* x   = (const float*)d_in[0];
    const float* fg  = (const float*)d_in[1];
    const float* bg  = (const float*)d_in[2];
    const float* w1  = (const float*)d_in[3];
    const float* g1  = (const float*)d_in[4];
    const float* b1  = (const float*)d_in[5];
    const float* m1  = (const float*)d_in[6];
    const float* v1  = (const float*)d_in[7];
    const float* w2  = (const float*)d_in[8];
    const float* g2  = (const float*)d_in[9];
    const float* b2  = (const float*)d_in[10];
    const float* m2  = (const float*)d_in[11];
    const float* v2  = (const float*)d_in[12];
    const float* Wv  = (const float*)d_in[13];
    const float* bv  = (const float*)d_in[14];
    const float* Wfg = (const float*)d_in[15];
    const float* bfg = (const float*)d_in[16];
    const float* Wbg = (const float*)d_in[17];
    const float* bbg = (const float*)d_in[18];
    const float* Wp  = (const float*)d_in[19];
    const float* bp  = (const float*)d_in[20];
    const float* w3  = (const float*)d_in[21];
    const float* g3  = (const float*)d_in[22];
    const float* b3  = (const float*)d_in[23];
    const float* m3  = (const float*)d_in[24];
    const float* v3  = (const float*)d_in[25];
    const float* w4  = (const float*)d_in[26];
    const float* g4  = (const float*)d_in[27];
    const float* b4  = (const float*)d_in[28];
    const float* m4  = (const float*)d_in[29];
    const float* v4  = (const float*)d_in[30];

    char* ws = (char*)d_ws;
    float* bufA = (float*)ws;                          // 32 MiB: B*256*HW f32
    float* bufB = (float*)(ws + (size_t)(32 << 20));   // 32 MiB
    float* attn = (float*)(ws + (size_t)(64 << 20));   // 9.44 MB: B*8*9*HW
    float* S    = (float*)(ws + (size_t)(64 << 20) + (size_t)(10 << 20)); // 1 MB

    const dim3 blk(256);
    const int PIX_BLOCKS = (BATCH * HW) / 256;   // 128

    // conv1: x(8,64,64,64) -> bufA(8,256,64,64)
    conv3x3_bn_relu<64, 16><<<dim3(PIX_BLOCKS, 16), blk, 0, stream>>>(
        x, w1, g1, b1, m1, v1, bufA, 256);
    // conv2: bufA -> bufB
    conv3x3_bn_relu<256, 16><<<dim3(PIX_BLOCKS, 16), blk, 0, stream>>>(
        bufA, w2, g2, b2, m2, v2, bufB, 256);
    // v = Wv @ h1 + bv : bufB -> bufA
    conv1x1_kernel<256, 16, false><<<dim3(PIX_BLOCKS, 16), blk, 0, stream>>>(
        bufB, Wv, bv, nullptr, bufA, 256);
    // attention softmax
    attn_kernel<<<dim3(PIX_BLOCKS), blk, 0, stream>>>(
        fg, bg, Wfg, bfg, Wbg, bbg, attn);
    // fold -> S
    fold_sum_kernel<<<dim3((BATCH * HEADS * HW) / 256), blk, 0, stream>>>(attn, S);
    // o = Wp @ (v * S) + bp : bufA -> bufB
    conv1x1_kernel<256, 16, true><<<dim3(PIX_BLOCKS, 16), blk, 0, stream>>>(
        bufA, Wp, bp, S, bufB, 256);
    // conv3: bufB -> bufA
    conv3x3_bn_relu<256, 16><<<dim3(PIX_BLOCKS, 16), blk, 0, stream>>>(
        bufB, w3, g3, b3, m3, v3, bufA, 256);
    // conv4: bufA -> d_out
    conv3x3_bn_relu<256, 16><<<dim3(PIX_BLOCKS, 16), blk, 0, stream>>>(
        bufA, w4, g4, b4, m4, v4, (float*)d_out, 256);
}

// Round 2
// 1254.153 us; speedup vs baseline: 2.4568x; 2.4568x over previous
//
#include <hip/hip_runtime.h>
#include <cstddef>
#include <cstdint>

#define BATCH 8
#define H_ 64
#define W_ 64
#define HW 4096
#define DIM 256
#define HEADS 8
#define KK 9
#define PADR 4356   // 66*66 padded rows per batch

typedef unsigned short u16;
typedef unsigned int u32;
typedef __attribute__((ext_vector_type(8))) short short8;
typedef __attribute__((ext_vector_type(4))) float f32x4;

constexpr float kEps = 1e-5f;
constexpr float kInvSqrtD = 0.17677669529663687f;  // 32^-0.5

__device__ __forceinline__ u16 f2bf(float f){
  u32 u = __float_as_uint(f);
  u = (u + 0x7fffu + ((u >> 16) & 1u)) >> 16;   // round-to-nearest-even
  return (u16)u;
}
__device__ __forceinline__ float bf2f(u16 h){ return __uint_as_float(((u32)h) << 16); }

__device__ __forceinline__ void gll16(const u16* g, u16* lds){
  __builtin_amdgcn_global_load_lds((const __attribute__((address_space(1))) u32*)g,
                                   (__attribute__((address_space(3))) u32*)lds, 16, 0, 0);
}

// ---------------------------------------------------------------------------
// Implicit-GEMM conv via bf16 MFMA with hi/lo split (3 MFMAs per product).
// A: padded pixel-major activations [B][4356][CIN] (hi,lo bf16), zero borders.
// W: packed weights [NTAP][256][CIN] (hi,lo bf16).
// Tile: BM=128 pixels x BN=64 oc, BK=32. 256 threads = 4 waves (2x2).
// EPI: 0 = BN+ReLU -> split store ; 1 = bias + S-mul -> split ;
//      2 = bias -> split ; 3 = BN+ReLU -> f32 d_out (channel-major)
// ---------------------------------------------------------------------------
template<int CIN, int NTAP, int EPI>
__global__ __launch_bounds__(256) void gemm_conv(
    const u16* __restrict__ Ahi, const u16* __restrict__ Alo,
    const u16* __restrict__ Whi, const u16* __restrict__ Wlo,
    const float* __restrict__ q0, const float* __restrict__ q1,
    const float* __restrict__ q2, const float* __restrict__ q3,
    const float* __restrict__ Smap,
    u16* __restrict__ Ohi, u16* __restrict__ Olo, float* __restrict__ Of32)
{
  static_assert(CIN % 32 == 0, "");
  __shared__ u16 smem[12288];  // bytes: Ahi 8K | Alo 8K | Bhi 4K | Blo 4K

  const int tid  = threadIdx.x;
  const int lane = tid & 63;
  const int wid  = tid >> 6;
  const int wm   = wid >> 1, wn = wid & 1;
  const int pix0 = blockIdx.x * 128;
  const int oc0  = blockIdx.y * 64;

  // --- staging source addresses (element offsets) ---
  const int ch8 = (tid & 3) * 8;
  int aoff[2];
  #pragma unroll
  for (int i = 0; i < 2; ++i){
    const int row = (tid + i * 256) >> 2;    // 0..127
    const int pix = pix0 + row;
    const int b = pix >> 12, yx = pix & 4095;
    const int y = yx >> 6, x = yx & 63;
    aoff[i] = (b * PADR + (y + 1) * 66 + (x + 1)) * CIN + ch8;
  }
  const int boff = (oc0 + (tid >> 2)) * CIN + ch8;

  // --- wave-uniform LDS destinations for global_load_lds ---
  u16* ldsAh0 = (u16*)((char*)smem + 0     + wid * 1024);
  u16* ldsAh1 = (u16*)((char*)smem + 4096  + wid * 1024);
  u16* ldsAl0 = (u16*)((char*)smem + 8192  + wid * 1024);
  u16* ldsAl1 = (u16*)((char*)smem + 12288 + wid * 1024);
  u16* ldsBh  = (u16*)((char*)smem + 16384 + wid * 1024);
  u16* ldsBl  = (u16*)((char*)smem + 20480 + wid * 1024);

  f32x4 acc[4][2];
  #pragma unroll
  for (int m = 0; m < 4; ++m)
    #pragma unroll
    for (int n = 0; n < 2; ++n)
      acc[m][n] = (f32x4){0.f, 0.f, 0.f, 0.f};

  constexpr int KCH = CIN / 32;
  constexpr int KSTEPS = NTAP * KCH;

  const int fr = lane & 15;         // fragment row within 16
  const int fc = (lane >> 4) * 8;   // fragment k-chunk

  for (int ks = 0; ks < KSTEPS; ++ks){
    const int t  = ks / KCH;
    const int kb = (ks % KCH) * 32;
    const int sh = (NTAP == 9) ? ((t / 3 - 1) * 66 + (t % 3 - 1)) : 0;
    const int ao = sh * CIN + kb;
    const int bo = t * 256 * CIN + kb;

    __syncthreads();   // previous compute done reading smem
    gll16(Ahi + aoff[0] + ao, ldsAh0);
    gll16(Ahi + aoff[1] + ao, ldsAh1);
    gll16(Alo + aoff[0] + ao, ldsAl0);
    gll16(Alo + aoff[1] + ao, ldsAl1);
    gll16(Whi + boff + bo, ldsBh);
    gll16(Wlo + boff + bo, ldsBl);
    __syncthreads();   // compiler drains vmcnt before barrier

    short8 ah[4], al[4];
    #pragma unroll
    for (int m = 0; m < 4; ++m){
      const int r = (wm * 64 + m * 16 + fr) * 32 + fc;
      ah[m] = *(const short8*)&smem[r];
      al[m] = *(const short8*)&smem[4096 + r];
    }
    #pragma unroll
    for (int n = 0; n < 2; ++n){
      const int rb = (wn * 32 + n * 16 + fr) * 32 + fc;
      short8 bh = *(const short8*)&smem[8192 + rb];
      short8 bl = *(const short8*)&smem[10240 + rb];
      #pragma unroll
      for (int m = 0; m < 4; ++m){
        acc[m][n] = __builtin_amdgcn_mfma_f32_16x16x32_bf16(ah[m], bh, acc[m][n], 0, 0, 0);
        acc[m][n] = __builtin_amdgcn_mfma_f32_16x16x32_bf16(al[m], bh, acc[m][n], 0, 0, 0);
        acc[m][n] = __builtin_amdgcn_mfma_f32_16x16x32_bf16(ah[m], bl, acc[m][n], 0, 0, 0);
      }
    }
  }

  // --- epilogue ---
  #pragma unroll
  for (int n = 0; n < 2; ++n){
    const int oc = oc0 + wn * 32 + n * 16 + fr;
    float sc, shv;
    if constexpr (EPI == 0 || EPI == 3){
      sc  = q0[oc] * rsqrtf(q3[oc] + kEps);
      shv = q1[oc] - q2[oc] * sc;
    } else {
      sc = 1.f; shv = q0[oc];
      (void)q1; (void)q2; (void)q3;
    }
    #pragma unroll
    for (int m = 0; m < 4; ++m){
      const int pixb = pix0 + wm * 64 + m * 16 + (lane >> 4) * 4;
      f32x4 a = acc[m][n];
      if constexpr (EPI == 3){
        const int b = pixb >> 12, yx = pixb & 4095;
        float4 o4;
        o4.x = fmaxf(fmaf(a[0], sc, shv), 0.f);
        o4.y = fmaxf(fmaf(a[1], sc, shv), 0.f);
        o4.z = fmaxf(fmaf(a[2], sc, shv), 0.f);
        o4.w = fmaxf(fmaf(a[3], sc, shv), 0.f);
        *(float4*)&Of32[((size_t)b * 256 + oc) * HW + yx] = o4;
      } else {
        #pragma unroll
        for (int r = 0; r < 4; ++r){
          const int pix = pixb + r;
          const int b = pix >> 12, yx = pix & 4095;
          const int y = yx >> 6, x = yx & 63;
          float v;
          if constexpr (EPI == 0)
            v = fmaxf(fmaf(a[r], sc, shv), 0.f);
          else if constexpr (EPI == 1)
            v = (a[r] + shv) * Smap[((size_t)b * HEADS + (oc >> 5)) * HW + yx];
          else
            v = a[r] + shv;
          const u16 h = f2bf(v);
          const u16 l = f2bf(v - bf2f(h));
          const size_t pr = ((size_t)b * PADR + (y + 1) * 66 + (x + 1)) * 256 + oc;
          Ohi[pr] = h; Olo[pr] = l;
        }
      }
    }
  }
}

// ---------------------------------------------------------------------------
// Weight pack: w flat [O=256][C][T] f32  ->  hi/lo bf16 [T][256][C]
// ---------------------------------------------------------------------------
__global__ __launch_bounds__(256) void pack_w(const float* __restrict__ w,
    u16* __restrict__ hi, u16* __restrict__ lo, int C, int T, int N)
{
  const int idx = blockIdx.x * 256 + threadIdx.x;
  if (idx >= N) return;
  const int o = idx / (C * T);
  const int rem = idx - o * C * T;
  const int c = rem / T;
  const int t = rem - c * T;
  const float v = w[idx];
  const u16 h = f2bf(v);
  const u16 l = f2bf(v - bf2f(h));
  const size_t dst = ((size_t)t * 256 + o) * C + c;
  hi[dst] = h; lo[dst] = l;
}

// ---------------------------------------------------------------------------
// Input pack: x f32 [8][64][4096] -> padded pixel-major hi/lo [8][4356][64]
// ---------------------------------------------------------------------------
__global__ __launch_bounds__(256) void pack_x64(const float* __restrict__ x,
    u16* __restrict__ hi, u16* __restrict__ lo)
{
  const int p = blockIdx.x * 256 + threadIdx.x;   // over B*HW
  const int b = p >> 12, yx = p & 4095;
  const int y = yx >> 6, xx = yx & 63;
  const size_t pr = ((size_t)b * PADR + (y + 1) * 66 + (xx + 1)) * 64;
  const float* xp = x + (size_t)b * 64 * HW + yx;
  #pragma unroll 8
  for (int c = 0; c < 64; c += 2){
    const float v0 = xp[(size_t)c * HW];
    const float v1 = xp[(size_t)(c + 1) * HW];
    const u16 h0 = f2bf(v0), h1 = f2bf(v1);
    const u16 l0 = f2bf(v0 - bf2f(h0)), l1 = f2bf(v1 - bf2f(h1));
    *(u32*)&hi[pr + c] = (u32)h0 | ((u32)h1 << 16);
    *(u32*)&lo[pr + c] = (u32)l0 | ((u32)l1 << 16);
  }
}

// ---------------------------------------------------------------------------
// attention logits + softmax (f32 direct; round-1 verified)
// ---------------------------------------------------------------------------
__global__ __launch_bounds__(256) void attn_kernel(
    const float* __restrict__ fg, const float* __restrict__ bg,
    const float* __restrict__ Wfg, const float* __restrict__ bfg,
    const float* __restrict__ Wbg, const float* __restrict__ bbg,
    float* __restrict__ attn)
{
  const int p  = blockIdx.x * 256 + threadIdx.x;
  const int b  = p >> 12;
  const int yx = p & 4095;

  float d[72];
  #pragma unroll
  for (int o = 0; o < 72; ++o) d[o] = bfg[o] - bbg[o];

  const float* fp = fg + (size_t)b * DIM * HW + yx;
  const float* gp = bg + (size_t)b * DIM * HW + yx;

  for (int c = 0; c < DIM; ++c){
    const float fv = fp[(size_t)c * HW];
    const float gv = gp[(size_t)c * HW];
    #pragma unroll
    for (int o = 0; o < 72; ++o){
      d[o] = fmaf(Wfg[(size_t)o * DIM + c], fv, d[o]);
      d[o] = fmaf(-Wbg[(size_t)o * DIM + c], gv, d[o]);
    }
  }

  #pragma unroll
  for (int h = 0; h < HEADS; ++h){
    float l[KK];
    #pragma unroll
    for (int k = 0; k < KK; ++k) l[k] = d[h * KK + k] * kInvSqrtD;
    float mx = l[0];
    #pragma unroll
    for (int k = 1; k < KK; ++k) mx = fmaxf(mx, l[k]);
    float e[KK], sum = 0.f;
    #pragma unroll
    for (int k = 0; k < KK; ++k){ e[k] = __expf(l[k] - mx); sum += e[k]; }
    const float inv = 1.f / sum;
    #pragma unroll
    for (int k = 0; k < KK; ++k)
      attn[(((size_t)b * HEADS + h) * KK + k) * HW + yx] = e[k] * inv;
  }
}

__global__ __launch_bounds__(256) void fold_sum_kernel(
    const float* __restrict__ attn, float* __restrict__ S)
{
  const int idx = blockIdx.x * 256 + threadIdx.x;  // over B*HEADS*HW
  const int bh  = idx >> 12;
  const int yx  = idx & 4095;
  const int y   = yx >> 6;
  const int x   = yx & 63;

  const float* ap = attn + (size_t)bh * KK * HW;
  float s = 0.f;
  #pragma unroll
  for (int i = 0; i < 3; ++i){
    const int ys = y + 1 - i;
    if (ys < 0 || ys >= H_) continue;
    #pragma unroll
    for (int j = 0; j < 3; ++j){
      const int xs = x + 1 - j;
      if (xs < 0 || xs >= W_) continue;
      s += ap[(size_t)(i * 3 + j) * HW + ys * W_ + xs];
    }
  }
  S[idx] = s;
}

// ---------------------------------------------------------------------------
extern "C" void kernel_launch(void* const* d_in, const int* in_sizes, int n_in,
                              void* d_out, int out_size, void* d_ws, size_t ws_size,
                              hipStream_t stream)
{
  const float* x   = (const float*)d_in[0];
  const float* fg  = (const float*)d_in[1];
  const float* bg  = (const float*)d_in[2];
  const float* w1  = (const float*)d_in[3];
  const float* g1  = (const float*)d_in[4];
  const float* b1  = (const float*)d_in[5];
  const float* m1  = (const float*)d_in[6];
  const float* v1  = (const float*)d_in[7];
  const float* w2  = (const float*)d_in[8];
  const float* g2  = (const float*)d_in[9];
  const float* b2  = (const float*)d_in[10];
  const float* m2  = (const float*)d_in[11];
  const float* v2  = (const float*)d_in[12];
  const float* Wv  = (const float*)d_in[13];
  const float* bv  = (const float*)d_in[14];
  const float* Wfg = (const float*)d_in[15];
  const float* bfg = (const float*)d_in[16];
  const float* Wbg = (const float*)d_in[17];
  const float* bbg = (const float*)d_in[18];
  const float* Wp  = (const float*)d_in[19];
  const float* bp  = (const float*)d_in[20];
  const float* w3  = (const float*)d_in[21];
  const float* g3  = (const float*)d_in[22];
  const float* b3  = (const float*)d_in[23];
  const float* m3  = (const float*)d_in[24];
  const float* v3  = (const float*)d_in[25];
  const float* w4  = (const float*)d_in[26];
  const float* g4  = (const float*)d_in[27];
  const float* b4  = (const float*)d_in[28];
  const float* m4  = (const float*)d_in[29];
  const float* v4  = (const float*)d_in[30];

  const size_t XB = (size_t)BATCH * PADR * 64 * 2;    // 4,460,544
  const size_t PB = (size_t)BATCH * PADR * 256 * 2;   // 17,842,176

  char* p = (char*)d_ws;
  u16* xpad_hi = (u16*)p;               p += XB;
  u16* xpad_lo = (u16*)p;               p += XB;
  u16* slA_hi  = (u16*)p;               p += PB;
  u16* slA_lo  = (u16*)p;               p += PB;
  u16* slB_hi  = (u16*)p;               p += PB;
  u16* slB_lo  = (u16*)p;               p += PB;
  u16* w1h = (u16*)p; p += 294912;  u16* w1l = (u16*)p; p += 294912;
  u16* w2h = (u16*)p; p += 1179648; u16* w2l = (u16*)p; p += 1179648;
  u16* w3h = (u16*)p; p += 1179648; u16* w3l = (u16*)p; p += 1179648;
  u16* w4h = (u16*)p; p += 1179648; u16* w4l = (u16*)p; p += 1179648;
  u16* wvh = (u16*)p; p += 131072;  u16* wvl = (u16*)p; p += 131072;
  u16* wph = (u16*)p; p += 131072;  u16* wpl = (u16*)p; p += 131072;
  float* attn = (float*)p;          p += (size_t)BATCH * HEADS * KK * HW * 4;
  float* S    = (float*)p;          p += (size_t)BATCH * HEADS * HW * 4;

  const dim3 blk(256);
  const int PIX_BLOCKS = (BATCH * HW) / 256;   // 128

  // zero padded activation tensors (borders must be 0 every call)
  hipMemsetAsync(xpad_hi, 0, 2 * XB, stream);
  hipMemsetAsync(slA_hi, 0, 2 * PB, stream);
  hipMemsetAsync(slB_hi, 0, 2 * PB, stream);

  // pack weights + input
  pack_w<<<dim3((147456 + 255) / 256), blk, 0, stream>>>(w1, w1h, w1l, 64, 9, 147456);
  pack_w<<<dim3((589824 + 255) / 256), blk, 0, stream>>>(w2, w2h, w2l, 256, 9, 589824);
  pack_w<<<dim3((589824 + 255) / 256), blk, 0, stream>>>(w3, w3h, w3l, 256, 9, 589824);
  pack_w<<<dim3((589824 + 255) / 256), blk, 0, stream>>>(w4, w4h, w4l, 256, 9, 589824);
  pack_w<<<dim3((65536 + 255) / 256), blk, 0, stream>>>(Wv, wvh, wvl, 256, 1, 65536);
  pack_w<<<dim3((65536 + 255) / 256), blk, 0, stream>>>(Wp, wph, wpl, 256, 1, 65536);
  pack_x64<<<dim3(PIX_BLOCKS), blk, 0, stream>>>(x, xpad_hi, xpad_lo);

  // attention path (independent of v-path)
  attn_kernel<<<dim3(PIX_BLOCKS), blk, 0, stream>>>(fg, bg, Wfg, bfg, Wbg, bbg, attn);
  fold_sum_kernel<<<dim3((BATCH * HEADS * HW) / 256), blk, 0, stream>>>(attn, S);

  const dim3 ggrid(256, 4);
  // conv1: xpad -> slotA (h1)
  gemm_conv<64, 9, 0><<<ggrid, blk, 0, stream>>>(
      xpad_hi, xpad_lo, w1h, w1l, g1, b1, m1, v1, nullptr, slA_hi, slA_lo, nullptr);
  // conv2: slotA -> slotB (h2)
  gemm_conv<256, 9, 0><<<ggrid, blk, 0, stream>>>(
      slA_hi, slA_lo, w2h, w2l, g2, b2, m2, v2, nullptr, slB_hi, slB_lo, nullptr);
  // Wv + S-mul: slotB -> slotA (v*S)
  gemm_conv<256, 1, 1><<<ggrid, blk, 0, stream>>>(
      slB_hi, slB_lo, wvh, wvl, bv, nullptr, nullptr, nullptr, S, slA_hi, slA_lo, nullptr);
  // Wp: slotA -> slotB (o)
  gemm_conv<256, 1, 2><<<ggrid, blk, 0, stream>>>(
      slA_hi, slA_lo, wph, wpl, bp, nullptr, nullptr, nullptr, nullptr, slB_hi, slB_lo, nullptr);
  // conv3: slotB -> slotA (h3)
  gemm_conv<256, 9, 0><<<ggrid, blk, 0, stream>>>(
      slB_hi, slB_lo, w3h, w3l, g3, b3, m3, v3, nullptr, slA_hi, slA_lo, nullptr);
  // conv4: slotA -> d_out (f32 channel-major)
  gemm_conv<256, 9, 3><<<ggrid, blk, 0, stream>>>(
      slA_hi, slA_lo, w4h, w4l, g4, b4, m4, v4, nullptr, nullptr, nullptr, (float*)d_out);
}

// Round 3
// 722.105 us; speedup vs baseline: 4.2670x; 1.7368x over previous
//
#include <hip/hip_runtime.h>
#include <cstddef>
#include <cstdint>

#define BATCH 8
#define H_ 64
#define W_ 64
#define HW 4096
#define DIM 256
#define HEADS 8
#define KK 9
#define PADR 4356   // 66*66 padded rows per batch

typedef unsigned short u16;
typedef unsigned int u32;
typedef __attribute__((ext_vector_type(8))) short short8;
typedef __attribute__((ext_vector_type(4))) float f32x4;

constexpr float kEps = 1e-5f;
constexpr float kInvSqrtD = 0.17677669529663687f;  // 32^-0.5

__device__ __forceinline__ u16 f2bf(float f){
  u32 u = __float_as_uint(f);
  u = (u + 0x7fffu + ((u >> 16) & 1u)) >> 16;   // round-to-nearest-even
  return (u16)u;
}
__device__ __forceinline__ float bf2f(u16 h){ return __uint_as_float(((u32)h) << 16); }

__device__ __forceinline__ void gll16(const u16* g, u16* lds){
  __builtin_amdgcn_global_load_lds((const __attribute__((address_space(1))) u32*)g,
                                   (__attribute__((address_space(3))) u32*)lds, 16, 0, 0);
}

// ---------------------------------------------------------------------------
// Implicit-GEMM conv via bf16 MFMA with hi/lo split (3 MFMAs per product).
// (verified round 2)
// ---------------------------------------------------------------------------
template<int CIN, int NTAP, int EPI>
__global__ __launch_bounds__(256) void gemm_conv(
    const u16* __restrict__ Ahi, const u16* __restrict__ Alo,
    const u16* __restrict__ Whi, const u16* __restrict__ Wlo,
    const float* __restrict__ q0, const float* __restrict__ q1,
    const float* __restrict__ q2, const float* __restrict__ q3,
    const float* __restrict__ Smap,
    u16* __restrict__ Ohi, u16* __restrict__ Olo, float* __restrict__ Of32)
{
  static_assert(CIN % 32 == 0, "");
  __shared__ u16 smem[12288];  // bytes: Ahi 8K | Alo 8K | Bhi 4K | Blo 4K

  const int tid  = threadIdx.x;
  const int lane = tid & 63;
  const int wid  = tid >> 6;
  const int wm   = wid >> 1, wn = wid & 1;
  const int pix0 = blockIdx.x * 128;
  const int oc0  = blockIdx.y * 64;

  const int ch8 = (tid & 3) * 8;
  int aoff[2];
  #pragma unroll
  for (int i = 0; i < 2; ++i){
    const int row = (tid + i * 256) >> 2;    // 0..127
    const int pix = pix0 + row;
    const int b = pix >> 12, yx = pix & 4095;
    const int y = yx >> 6, x = yx & 63;
    aoff[i] = (b * PADR + (y + 1) * 66 + (x + 1)) * CIN + ch8;
  }
  const int boff = (oc0 + (tid >> 2)) * CIN + ch8;

  u16* ldsAh0 = (u16*)((char*)smem + 0     + wid * 1024);
  u16* ldsAh1 = (u16*)((char*)smem + 4096  + wid * 1024);
  u16* ldsAl0 = (u16*)((char*)smem + 8192  + wid * 1024);
  u16* ldsAl1 = (u16*)((char*)smem + 12288 + wid * 1024);
  u16* ldsBh  = (u16*)((char*)smem + 16384 + wid * 1024);
  u16* ldsBl  = (u16*)((char*)smem + 20480 + wid * 1024);

  f32x4 acc[4][2];
  #pragma unroll
  for (int m = 0; m < 4; ++m)
    #pragma unroll
    for (int n = 0; n < 2; ++n)
      acc[m][n] = (f32x4){0.f, 0.f, 0.f, 0.f};

  constexpr int KCH = CIN / 32;
  constexpr int KSTEPS = NTAP * KCH;

  const int fr = lane & 15;
  const int fc = (lane >> 4) * 8;

  for (int ks = 0; ks < KSTEPS; ++ks){
    const int t  = ks / KCH;
    const int kb = (ks % KCH) * 32;
    const int sh = (NTAP == 9) ? ((t / 3 - 1) * 66 + (t % 3 - 1)) : 0;
    const int ao = sh * CIN + kb;
    const int bo = t * 256 * CIN + kb;

    __syncthreads();
    gll16(Ahi + aoff[0] + ao, ldsAh0);
    gll16(Ahi + aoff[1] + ao, ldsAh1);
    gll16(Alo + aoff[0] + ao, ldsAl0);
    gll16(Alo + aoff[1] + ao, ldsAl1);
    gll16(Whi + boff + bo, ldsBh);
    gll16(Wlo + boff + bo, ldsBl);
    __syncthreads();

    short8 ah[4], al[4];
    #pragma unroll
    for (int m = 0; m < 4; ++m){
      const int r = (wm * 64 + m * 16 + fr) * 32 + fc;
      ah[m] = *(const short8*)&smem[r];
      al[m] = *(const short8*)&smem[4096 + r];
    }
    #pragma unroll
    for (int n = 0; n < 2; ++n){
      const int rb = (wn * 32 + n * 16 + fr) * 32 + fc;
      short8 bh = *(const short8*)&smem[8192 + rb];
      short8 bl = *(const short8*)&smem[10240 + rb];
      #pragma unroll
      for (int m = 0; m < 4; ++m){
        acc[m][n] = __builtin_amdgcn_mfma_f32_16x16x32_bf16(ah[m], bh, acc[m][n], 0, 0, 0);
        acc[m][n] = __builtin_amdgcn_mfma_f32_16x16x32_bf16(al[m], bh, acc[m][n], 0, 0, 0);
        acc[m][n] = __builtin_amdgcn_mfma_f32_16x16x32_bf16(ah[m], bl, acc[m][n], 0, 0, 0);
      }
    }
  }

  #pragma unroll
  for (int n = 0; n < 2; ++n){
    const int oc = oc0 + wn * 32 + n * 16 + fr;
    float sc, shv;
    if constexpr (EPI == 0 || EPI == 3){
      sc  = q0[oc] * rsqrtf(q3[oc] + kEps);
      shv = q1[oc] - q2[oc] * sc;
    } else {
      sc = 1.f; shv = q0[oc];
      (void)q1; (void)q2; (void)q3;
    }
    #pragma unroll
    for (int m = 0; m < 4; ++m){
      const int pixb = pix0 + wm * 64 + m * 16 + (lane >> 4) * 4;
      f32x4 a = acc[m][n];
      if constexpr (EPI == 3){
        const int b = pixb >> 12, yx = pixb & 4095;
        float4 o4;
        o4.x = fmaxf(fmaf(a[0], sc, shv), 0.f);
        o4.y = fmaxf(fmaf(a[1], sc, shv), 0.f);
        o4.z = fmaxf(fmaf(a[2], sc, shv), 0.f);
        o4.w = fmaxf(fmaf(a[3], sc, shv), 0.f);
        *(float4*)&Of32[((size_t)b * 256 + oc) * HW + yx] = o4;
      } else {
        #pragma unroll
        for (int r = 0; r < 4; ++r){
          const int pix = pixb + r;
          const int b = pix >> 12, yx = pix & 4095;
          const int y = yx >> 6, x = yx & 63;
          float v;
          if constexpr (EPI == 0)
            v = fmaxf(fmaf(a[r], sc, shv), 0.f);
          else if constexpr (EPI == 1)
            v = (a[r] + shv) * Smap[((size_t)b * HEADS + (oc >> 5)) * HW + yx];
          else
            v = a[r] + shv;
          const u16 h = f2bf(v);
          const u16 l = f2bf(v - bf2f(h));
          const size_t pr = ((size_t)b * PADR + (y + 1) * 66 + (x + 1)) * 256 + oc;
          Ohi[pr] = h; Olo[pr] = l;
        }
      }
    }
  }
}

// ---------------------------------------------------------------------------
// Weight pack: w flat [O=256][C][T] f32  ->  hi/lo bf16 [T][256][C]
// ---------------------------------------------------------------------------
__global__ __launch_bounds__(256) void pack_w(const float* __restrict__ w,
    u16* __restrict__ hi, u16* __restrict__ lo, int C, int T, int N)
{
  const int idx = blockIdx.x * 256 + threadIdx.x;
  if (idx >= N) return;
  const int o = idx / (C * T);
  const int rem = idx - o * C * T;
  const int c = rem / T;
  const int t = rem - c * T;
  const float v = w[idx];
  const u16 h = f2bf(v);
  const u16 l = f2bf(v - bf2f(h));
  const size_t dst = ((size_t)t * 256 + o) * C + c;
  hi[dst] = h; lo[dst] = l;
}

// ---------------------------------------------------------------------------
// Input pack: x f32 [8][64][4096] -> padded pixel-major hi/lo [8][4356][64]
// ---------------------------------------------------------------------------
__global__ __launch_bounds__(256) void pack_x64(const float* __restrict__ x,
    u16* __restrict__ hi, u16* __restrict__ lo)
{
  const int p = blockIdx.x * 256 + threadIdx.x;   // over B*HW
  const int b = p >> 12, yx = p & 4095;
  const int y = yx >> 6, xx = yx & 63;
  const size_t pr = ((size_t)b * PADR + (y + 1) * 66 + (xx + 1)) * 64;
  const float* xp = x + (size_t)b * 64 * HW + yx;
  #pragma unroll 8
  for (int c = 0; c < 64; c += 2){
    const float v0 = xp[(size_t)c * HW];
    const float v1 = xp[(size_t)(c + 1) * HW];
    const u16 h0 = f2bf(v0), h1 = f2bf(v1);
    const u16 l0 = f2bf(v0 - bf2f(h0)), l1 = f2bf(v1 - bf2f(h1));
    *(u32*)&hi[pr + c] = (u32)h0 | ((u32)h1 << 16);
    *(u32*)&lo[pr + c] = (u32)l0 | ((u32)l1 << 16);
  }
}

// ---------------------------------------------------------------------------
// pack fg,bg (f32 channel-major) -> G[32768][512] bf16 pixel-major.
// cols 0..255 = fg channels, 256..511 = bg channels.
// LDS transpose: coalesced reads (lane=pixel) and 64B-chunk writes.
// ---------------------------------------------------------------------------
__global__ __launch_bounds__(256) void pack_fgbg(
    const float* __restrict__ fg, const float* __restrict__ bg,
    u16* __restrict__ G)
{
  __shared__ u16 sh[64 * 32];
  const int t = threadIdx.x;
  const int pix0 = blockIdx.x * 64;
  const int pl = t & 63;
  const int cg = (t >> 6) * 8;
  const int pix = pix0 + pl;
  const int b = pix >> 12, yx = pix & 4095;

  for (int chunk = 0; chunk < 512; chunk += 32){
    #pragma unroll
    for (int i = 0; i < 8; ++i){
      const int c = chunk + cg + i;
      const float v = (c < 256)
          ? fg[((size_t)b * 256 + c) * HW + yx]
          : bg[((size_t)b * 256 + (c - 256)) * HW + yx];
      sh[pl * 32 + cg + i] = f2bf(v);
    }
    __syncthreads();
    const int row = t >> 2, off = (t & 3) * 8;
    *(short8*)&G[(size_t)(pix0 + row) * 512 + chunk + off] =
        *(const short8*)&sh[row * 32 + off];
    __syncthreads();
  }
}

// ---------------------------------------------------------------------------
// pack Wcat[80][512] bf16: row o<72: cols<256 = Wfg[o][c], cols>=256 = -Wbg.
// rows 72..79 zeroed by memset beforehand.
// ---------------------------------------------------------------------------
__global__ __launch_bounds__(256) void pack_wcat(
    const float* __restrict__ Wfg, const float* __restrict__ Wbg,
    u16* __restrict__ Wcat)
{
  const int idx = blockIdx.x * 256 + threadIdx.x;
  if (idx >= 72 * 512) return;
  const int o = idx >> 9, c = idx & 511;
  const float v = (c < 256) ? Wfg[o * 256 + c] : -Wbg[o * 256 + (c - 256)];
  Wcat[idx] = f2bf(v);
}

// ---------------------------------------------------------------------------
// attn logits GEMM: Lg[32768][72] = G[32768][512] @ Wcat[80][512]^T + bias
// BM=128 (4 waves x 32 rows), BN=80 (5 n-tiles), BK=32, plain bf16.
// B fragments read directly from global (L2-resident, 80KB).
// ---------------------------------------------------------------------------
__global__ __launch_bounds__(256) void attn_gemm(
    const u16* __restrict__ G, const u16* __restrict__ Wcat,
    const float* __restrict__ bfg, const float* __restrict__ bbg,
    float* __restrict__ Lg)
{
  __shared__ u16 smem[4096];  // 128 rows x 32 ch bf16 = 8KB

  const int tid  = threadIdx.x;
  const int lane = tid & 63;
  const int wid  = tid >> 6;
  const int pix0 = blockIdx.x * 128;

  const int ch8 = (tid & 3) * 8;
  int aoff[2];
  #pragma unroll
  for (int i = 0; i < 2; ++i){
    const int row = (tid + i * 256) >> 2;    // 0..127
    aoff[i] = (pix0 + row) * 512 + ch8;
  }

  u16* ldsA0 = (u16*)((char*)smem + 0    + wid * 1024);
  u16* ldsA1 = (u16*)((char*)smem + 4096 + wid * 1024);

  f32x4 acc[2][5];
  #pragma unroll
  for (int m = 0; m < 2; ++m)
    #pragma unroll
    for (int n = 0; n < 5; ++n)
      acc[m][n] = (f32x4){0.f, 0.f, 0.f, 0.f};

  const int fr = lane & 15;
  const int fc = (lane >> 4) * 8;

  for (int ks = 0; ks < 16; ++ks){
    const int kb = ks * 32;
    __syncthreads();
    gll16(G + aoff[0] + kb, ldsA0);
    gll16(G + aoff[1] + kb, ldsA1);
    __syncthreads();

    short8 a[2];
    #pragma unroll
    for (int m = 0; m < 2; ++m){
      const int r = (wid * 32 + m * 16 + fr) * 32 + fc;
      a[m] = *(const short8*)&smem[r];
    }
    #pragma unroll
    for (int n = 0; n < 5; ++n){
      const int oc = n * 16 + fr;
      short8 bfrag = *(const short8*)&Wcat[(size_t)oc * 512 + kb + fc];
      #pragma unroll
      for (int m = 0; m < 2; ++m)
        acc[m][n] = __builtin_amdgcn_mfma_f32_16x16x32_bf16(a[m], bfrag, acc[m][n], 0, 0, 0);
    }
  }

  #pragma unroll
  for (int n = 0; n < 5; ++n){
    const int col = n * 16 + fr;
    if (col >= 72) continue;
    const float bias = bfg[col] - bbg[col];
    #pragma unroll
    for (int m = 0; m < 2; ++m){
      #pragma unroll
      for (int r = 0; r < 4; ++r){
        const int pix = pix0 + wid * 32 + m * 16 + (lane >> 4) * 4 + r;
        Lg[(size_t)pix * 72 + col] = acc[m][n][r] + bias;
      }
    }
  }
}

// ---------------------------------------------------------------------------
// softmax: Lg[pix][72] -> attn[b][h][kk][yx] (channel-major, as round-1 fold)
// ---------------------------------------------------------------------------
__global__ __launch_bounds__(256) void softmax_kernel(
    const float* __restrict__ Lg, float* __restrict__ attn)
{
  const int p  = blockIdx.x * 256 + threadIdx.x;
  const int b  = p >> 12;
  const int yx = p & 4095;

  float d[72];
  #pragma unroll
  for (int i = 0; i < 18; ++i)
    *(float4*)&d[i * 4] = *(const float4*)&Lg[(size_t)p * 72 + i * 4];

  #pragma unroll
  for (int h = 0; h < HEADS; ++h){
    float l[KK];
    #pragma unroll
    for (int k = 0; k < KK; ++k) l[k] = d[h * KK + k] * kInvSqrtD;
    float mx = l[0];
    #pragma unroll
    for (int k = 1; k < KK; ++k) mx = fmaxf(mx, l[k]);
    float e[KK], sum = 0.f;
    #pragma unroll
    for (int k = 0; k < KK; ++k){ e[k] = __expf(l[k] - mx); sum += e[k]; }
    const float inv = 1.f / sum;
    #pragma unroll
    for (int k = 0; k < KK; ++k)
      attn[(((size_t)b * HEADS + h) * KK + k) * HW + yx] = e[k] * inv;
  }
}

__global__ __launch_bounds__(256) void fold_sum_kernel(
    const float* __restrict__ attn, float* __restrict__ S)
{
  const int idx = blockIdx.x * 256 + threadIdx.x;  // over B*HEADS*HW
  const int bh  = idx >> 12;
  const int yx  = idx & 4095;
  const int y   = yx >> 6;
  const int x   = yx & 63;

  const float* ap = attn + (size_t)bh * KK * HW;
  float s = 0.f;
  #pragma unroll
  for (int i = 0; i < 3; ++i){
    const int ys = y + 1 - i;
    if (ys < 0 || ys >= H_) continue;
    #pragma unroll
    for (int j = 0; j < 3; ++j){
      const int xs = x + 1 - j;
      if (xs < 0 || xs >= W_) continue;
      s += ap[(size_t)(i * 3 + j) * HW + ys * W_ + xs];
    }
  }
  S[idx] = s;
}

// ---------------------------------------------------------------------------
extern "C" void kernel_launch(void* const* d_in, const int* in_sizes, int n_in,
                              void* d_out, int out_size, void* d_ws, size_t ws_size,
                              hipStream_t stream)
{
  const float* x   = (const float*)d_in[0];
  const float* fg  = (const float*)d_in[1];
  const float* bg  = (const float*)d_in[2];
  const float* w1  = (const float*)d_in[3];
  const float* g1  = (const float*)d_in[4];
  const float* b1  = (const float*)d_in[5];
  const float* m1  = (const float*)d_in[6];
  const float* v1  = (const float*)d_in[7];
  const float* w2  = (const float*)d_in[8];
  const float* g2  = (const float*)d_in[9];
  const float* b2  = (const float*)d_in[10];
  const float* m2  = (const float*)d_in[11];
  const float* v2  = (const float*)d_in[12];
  const float* Wv  = (const float*)d_in[13];
  const float* bv  = (const float*)d_in[14];
  const float* Wfg = (const float*)d_in[15];
  const float* bfg = (const float*)d_in[16];
  const float* Wbg = (const float*)d_in[17];
  const float* bbg = (const float*)d_in[18];
  const float* Wp  = (const float*)d_in[19];
  const float* bp  = (const float*)d_in[20];
  const float* w3  = (const float*)d_in[21];
  const float* g3  = (const float*)d_in[22];
  const float* b3  = (const float*)d_in[23];
  const float* m3  = (const float*)d_in[24];
  const float* v3  = (const float*)d_in[25];
  const float* w4  = (const float*)d_in[26];
  const float* g4  = (const float*)d_in[27];
  const float* b4  = (const float*)d_in[28];
  const float* m4  = (const float*)d_in[29];
  const float* v4  = (const float*)d_in[30];

  const size_t XB = (size_t)BATCH * PADR * 64 * 2;    // 4,460,544
  const size_t PB = (size_t)BATCH * PADR * 256 * 2;   // 17,842,176

  char* p = (char*)d_ws;
  u16* xpad_hi = (u16*)p;               p += XB;
  u16* xpad_lo = (u16*)p;               p += XB;
  u16* slA_hi  = (u16*)p;               p += PB;
  u16* slA_lo  = (u16*)p;               p += PB;
  u16* slB_hi  = (u16*)p;               p += PB;
  u16* slB_lo  = (u16*)p;               p += PB;
  u16* w1h = (u16*)p; p += 294912;  u16* w1l = (u16*)p; p += 294912;
  u16* w2h = (u16*)p; p += 1179648; u16* w2l = (u16*)p; p += 1179648;
  u16* w3h = (u16*)p; p += 1179648; u16* w3l = (u16*)p; p += 1179648;
  u16* w4h = (u16*)p; p += 1179648; u16* w4l = (u16*)p; p += 1179648;
  u16* wvh = (u16*)p; p += 131072;  u16* wvl = (u16*)p; p += 131072;
  u16* wph = (u16*)p; p += 131072;  u16* wpl = (u16*)p; p += 131072;
  u16* wcat = (u16*)p;              p += 80 * 512 * 2;
  float* attn = (float*)p;          p += (size_t)BATCH * HEADS * KK * HW * 4;
  float* S    = (float*)p;          p += (size_t)BATCH * HEADS * HW * 4;

  // attn-path temporaries alias the conv slots (dead until conv1/conv2 run):
  u16*   G  = slA_hi;           // 33.5 MB <= 35.7 MB slA region
  float* Lg = (float*)slB_hi;   // 9.4 MB  <= 35.7 MB slB region

  const dim3 blk(256);
  const int PIX_BLOCKS = (BATCH * HW) / 256;   // 128

  // ---- packs that don't alias anything ----
  hipMemsetAsync(xpad_hi, 0, 2 * XB, stream);
  hipMemsetAsync(wcat, 0, 80 * 512 * 2, stream);
  pack_w<<<dim3((147456 + 255) / 256), blk, 0, stream>>>(w1, w1h, w1l, 64, 9, 147456);
  pack_w<<<dim3((589824 + 255) / 256), blk, 0, stream>>>(w2, w2h, w2l, 256, 9, 589824);
  pack_w<<<dim3((589824 + 255) / 256), blk, 0, stream>>>(w3, w3h, w3l, 256, 9, 589824);
  pack_w<<<dim3((589824 + 255) / 256), blk, 0, stream>>>(w4, w4h, w4l, 256, 9, 589824);
  pack_w<<<dim3((65536 + 255) / 256), blk, 0, stream>>>(Wv, wvh, wvl, 256, 1, 65536);
  pack_w<<<dim3((65536 + 255) / 256), blk, 0, stream>>>(Wp, wph, wpl, 256, 1, 65536);
  pack_wcat<<<dim3(144), blk, 0, stream>>>(Wfg, Wbg, wcat);
  pack_x64<<<dim3(PIX_BLOCKS), blk, 0, stream>>>(x, xpad_hi, xpad_lo);

  // ---- attention path (uses G/Lg aliased over slA/slB) ----
  pack_fgbg<<<dim3((BATCH * HW) / 64), blk, 0, stream>>>(fg, bg, G);
  attn_gemm<<<dim3((BATCH * HW) / 128), blk, 0, stream>>>(G, wcat, bfg, bbg, Lg);
  softmax_kernel<<<dim3(PIX_BLOCKS), blk, 0, stream>>>(Lg, attn);
  fold_sum_kernel<<<dim3((BATCH * HEADS * HW) / 256), blk, 0, stream>>>(attn, S);

  // ---- now safe to zero conv slots (kills G/Lg) ----
  hipMemsetAsync(slA_hi, 0, 2 * PB, stream);
  hipMemsetAsync(slB_hi, 0, 2 * PB, stream);

  const dim3 ggrid(256, 4);
  // conv1: xpad -> slotA (h1)
  gemm_conv<64, 9, 0><<<ggrid, blk, 0, stream>>>(
      xpad_hi, xpad_lo, w1h, w1l, g1, b1, m1, v1, nullptr, slA_hi, slA_lo, nullptr);
  // conv2: slotA -> slotB (h2)
  gemm_conv<256, 9, 0><<<ggrid, blk, 0, stream>>>(
      slA_hi, slA_lo, w2h, w2l, g2, b2, m2, v2, nullptr, slB_hi, slB_lo, nullptr);
  // Wv + S-mul: slotB -> slotA (v*S)
  gemm_conv<256, 1, 1><<<ggrid, blk, 0, stream>>>(
      slB_hi, slB_lo, wvh, wvl, bv, nullptr, nullptr, nullptr, S, slA_hi, slA_lo, nullptr);
  // Wp: slotA -> slotB (o)
  gemm_conv<256, 1, 2><<<ggrid, blk, 0, stream>>>(
      slA_hi, slA_lo, wph, wpl, bp, nullptr, nullptr, nullptr, nullptr, slB_hi, slB_lo, nullptr);
  // conv3: slotB -> slotA (h3)
  gemm_conv<256, 9, 0><<<ggrid, blk, 0, stream>>>(
      slB_hi, slB_lo, w3h, w3l, g3, b3, m3, v3, nullptr, slA_hi, slA_lo, nullptr);
  // conv4: slotA -> d_out (f32 channel-major)
  gemm_conv<256, 9, 3><<<ggrid, blk, 0, stream>>>(
      slA_hi, slA_lo, w4h, w4l, g4, b4, m4, v4, nullptr, nullptr, nullptr, (float*)d_out);
}

// Round 4
// 279.750 us; speedup vs baseline: 11.0143x; 2.5813x over previous
//
#include <hip/hip_runtime.h>
#include <cstddef>

#define BATCH 8
#define H_ 64
#define W_ 64
#define HW 4096
#define DIM 256
#define HEADS 8
#define KK 9
#define PADR 4356   // 66*66 padded pixels per batch

typedef unsigned short u16;
typedef unsigned int u32;
typedef __attribute__((ext_vector_type(8))) short short8;      // 8 bf16
typedef _Float16 __attribute__((ext_vector_type(8))) h8;       // 8 f16
typedef __attribute__((ext_vector_type(4))) float f32x4;

constexpr float kEps = 1e-5f;
constexpr float kInvSqrtD = 0.17677669529663687f;  // 32^-0.5

__device__ __forceinline__ u16 f2bf(float f){
  u32 u = __float_as_uint(f);
  u = (u + 0x7fffu + ((u >> 16) & 1u)) >> 16;
  return (u16)u;
}
__device__ __forceinline__ u16 f2h(float f){
  union { _Float16 h; u16 u; } cv;
  cv.h = (_Float16)f;                  // RNE f32->f16
  return cv.u;
}

__device__ __forceinline__ void gll16(const u16* g, u16* lds){
  __builtin_amdgcn_global_load_lds((const __attribute__((address_space(1))) u32*)g,
                                   (__attribute__((address_space(3))) u32*)lds, 16, 0, 0);
}

// ---------------------------------------------------------------------------
// Implicit-GEMM conv, plain f16 MFMA.
// A: padded pixel-major activations [B][4356][CIN] f16, zero borders.
// W: packed weights [NTAP][256][CIN] f16.
// Tile: BM=128 px x BN=128 oc, BK=64. 256 thr = 4 waves (2x2), wave=64x64 out.
// LDS: double buffer x (A[128][64] 16K + B[128][64] 16K) = 64 KB.
// Swizzle: 16B-chunk index ^= (row&7); staged via pre-swizzled global source
// (linear gll dest), read back with the same XOR (involution).
// 2-phase pipeline: issue next-tile gll before current ds_read+MFMA; one
// __syncthreads (vmcnt+lgkm drain) per K-step.
// EPI: 0 BN+ReLU->f16 pad ; 1 (x+b)*S->f16 pad ; 2 x+b->f16 pad ;
//      3 BN+ReLU->f32 d_out (channel-major)
// ---------------------------------------------------------------------------
template<int CIN, int NTAP, int EPI>
__global__ __launch_bounds__(256, 2) void gemm_conv(
    const u16* __restrict__ Act, const u16* __restrict__ Wt,
    const float* __restrict__ q0, const float* __restrict__ q1,
    const float* __restrict__ q2, const float* __restrict__ q3,
    const float* __restrict__ Smap,
    u16* __restrict__ Opad, float* __restrict__ Of32)
{
  constexpr int KCH = CIN / 64;          // 64-ch chunks per tap
  constexpr int KSTEPS = NTAP * KCH;
  __shared__ u16 smem[32768];            // 2 x (A 8192 + B 8192) elements

  const int tid  = threadIdx.x;
  const int lane = tid & 63;
  const int wid  = tid >> 6;
  const int wm   = wid >> 1, wn = wid & 1;
  const int fr   = lane & 15;
  const int g    = lane >> 4;
  const int pix0 = blockIdx.x * 128;
  const int oc0  = blockIdx.y * 128;

  // --- staging sources (inverse-swizzled so linear LDS dest => swizzled tile)
  const int csw = ((tid & 7) ^ ((tid >> 3) & 7)) << 3;   // element offset
  int a_src[4], b_src[4];
  #pragma unroll
  for (int q = 0; q < 4; ++q){
    const int r = q * 32 + (tid >> 3);        // tile row 0..127
    const int pix = pix0 + r;
    const int b = pix >> 12, yx = pix & 4095;
    const int y = yx >> 6, x = yx & 63;
    a_src[q] = (b * PADR + (y + 1) * 66 + (x + 1)) * CIN + csw;
    b_src[q] = (oc0 + r) * CIN + csw;
  }

  f32x4 acc[4][4];
  #pragma unroll
  for (int m = 0; m < 4; ++m)
    #pragma unroll
    for (int n = 0; n < 4; ++n)
      acc[m][n] = (f32x4){0.f, 0.f, 0.f, 0.f};

  auto stage = [&](int ks, int bsel){
    const int t  = (KCH == 1) ? ks : (ks / KCH);
    const int kb = (KCH == 1) ? 0  : ((ks % KCH) << 6);
    int ao = kb;
    if constexpr (NTAP == 9) ao += ((t / 3 - 1) * 66 + (t % 3 - 1)) * CIN;
    const int bo = t * (256 * CIN) + kb;
    u16* lA = smem + bsel * 16384 + wid * 512;
    u16* lB = lA + 8192;
    #pragma unroll
    for (int q = 0; q < 4; ++q){
      gll16(Act + a_src[q] + ao, lA + q * 2048);
      gll16(Wt  + b_src[q] + bo, lB + q * 2048);
    }
  };

  stage(0, 0);
  __syncthreads();

  for (int ks = 0; ks < KSTEPS; ++ks){
    const int bsel = ks & 1;
    if (ks + 1 < KSTEPS) stage(ks + 1, bsel ^ 1);   // prefetch next K-tile

    const u16* base = smem + bsel * 16384;
    h8 a[4][2], bb[4][2];
    #pragma unroll
    for (int m = 0; m < 4; ++m){
      const int R = wm * 64 + m * 16 + fr;
      #pragma unroll
      for (int kk = 0; kk < 2; ++kk)
        a[m][kk] = *(const h8*)&base[R * 64 + ((((kk << 2) + g) ^ (fr & 7)) << 3)];
    }
    #pragma unroll
    for (int n = 0; n < 4; ++n){
      const int R = wn * 64 + n * 16 + fr;
      #pragma unroll
      for (int kk = 0; kk < 2; ++kk)
        bb[n][kk] = *(const h8*)&base[8192 + R * 64 + ((((kk << 2) + g) ^ (fr & 7)) << 3)];
    }
    #pragma unroll
    for (int kk = 0; kk < 2; ++kk)
      #pragma unroll
      for (int n = 0; n < 4; ++n)
        #pragma unroll
        for (int m = 0; m < 4; ++m)
          acc[m][n] = __builtin_amdgcn_mfma_f32_16x16x32_f16(a[m][kk], bb[n][kk], acc[m][n], 0, 0, 0);

    __syncthreads();   // drains this step's prefetch vmcnt + protects buffers
  }

  // --- epilogue ---
  #pragma unroll
  for (int n = 0; n < 4; ++n){
    const int oc = oc0 + wn * 64 + n * 16 + fr;
    float sc, shv;
    if constexpr (EPI == 0 || EPI == 3){
      sc  = q0[oc] * rsqrtf(q3[oc] + kEps);
      shv = q1[oc] - q2[oc] * sc;
    } else {
      sc = 1.f; shv = q0[oc];
      (void)q1; (void)q2; (void)q3;
    }
    #pragma unroll
    for (int m = 0; m < 4; ++m){
      const int pixb = pix0 + wm * 64 + m * 16 + g * 4;
      f32x4 aa = acc[m][n];
      if constexpr (EPI == 3){
        const int b = pixb >> 12, yx = pixb & 4095;
        float4 o4;
        o4.x = fmaxf(fmaf(aa[0], sc, shv), 0.f);
        o4.y = fmaxf(fmaf(aa[1], sc, shv), 0.f);
        o4.z = fmaxf(fmaf(aa[2], sc, shv), 0.f);
        o4.w = fmaxf(fmaf(aa[3], sc, shv), 0.f);
        *(float4*)&Of32[((size_t)b * 256 + oc) * HW + yx] = o4;
      } else {
        #pragma unroll
        for (int r = 0; r < 4; ++r){
          const int pix = pixb + r;
          const int b = pix >> 12, yx = pix & 4095;
          const int y = yx >> 6, x = yx & 63;
          float v;
          if constexpr (EPI == 0)
            v = fmaxf(fmaf(aa[r], sc, shv), 0.f);
          else if constexpr (EPI == 1)
            v = (aa[r] + shv) * Smap[((size_t)b * HEADS + (oc >> 5)) * HW + yx];
          else
            v = aa[r] + shv;
          Opad[((size_t)b * PADR + (y + 1) * 66 + (x + 1)) * 256 + oc] = f2h(v);
        }
      }
    }
  }
}

// ---------------------------------------------------------------------------
// Weight pack: w flat [O=256][C][T] f32 -> f16 [T][256][C]
// ---------------------------------------------------------------------------
__global__ __launch_bounds__(256) void pack_w_f16(const float* __restrict__ w,
    u16* __restrict__ dst, int C, int T, int N)
{
  const int idx = blockIdx.x * 256 + threadIdx.x;
  if (idx >= N) return;
  const int o = idx / (C * T);
  const int rem = idx - o * C * T;
  const int c = rem / T;
  const int t = rem - c * T;
  dst[((size_t)t * 256 + o) * C + c] = f2h(w[idx]);
}

// ---------------------------------------------------------------------------
// Input pack: x f32 [8][64][4096] -> padded pixel-major f16 [8][4356][64]
// ---------------------------------------------------------------------------
__global__ __launch_bounds__(256) void pack_x64(const float* __restrict__ x,
    u16* __restrict__ xp)
{
  const int p = blockIdx.x * 256 + threadIdx.x;
  const int b = p >> 12, yx = p & 4095;
  const int y = yx >> 6, xx = yx & 63;
  const size_t pr = ((size_t)b * PADR + (y + 1) * 66 + (xx + 1)) * 64;
  const float* xs = x + (size_t)b * 64 * HW + yx;
  #pragma unroll 8
  for (int c = 0; c < 64; c += 2){
    const u16 h0 = f2h(xs[(size_t)c * HW]);
    const u16 h1 = f2h(xs[(size_t)(c + 1) * HW]);
    *(u32*)&xp[pr + c] = (u32)h0 | ((u32)h1 << 16);
  }
}

// ---------------------------------------------------------------------------
// attention path (verified round 3, bf16): pack fg/bg, logits GEMM, softmax,
// fold-sum collapse.
// ---------------------------------------------------------------------------
__global__ __launch_bounds__(256) void pack_fgbg(
    const float* __restrict__ fg, const float* __restrict__ bg,
    u16* __restrict__ G)
{
  __shared__ u16 sh[64 * 32];
  const int t = threadIdx.x;
  const int pix0 = blockIdx.x * 64;
  const int pl = t & 63;
  const int cg = (t >> 6) * 8;
  const int pix = pix0 + pl;
  const int b = pix >> 12, yx = pix & 4095;

  for (int chunk = 0; chunk < 512; chunk += 32){
    #pragma unroll
    for (int i = 0; i < 8; ++i){
      const int c = chunk + cg + i;
      const float v = (c < 256)
          ? fg[((size_t)b * 256 + c) * HW + yx]
          : bg[((size_t)b * 256 + (c - 256)) * HW + yx];
      sh[pl * 32 + cg + i] = f2bf(v);
    }
    __syncthreads();
    const int row = t >> 2, off = (t & 3) * 8;
    *(short8*)&G[(size_t)(pix0 + row) * 512 + chunk + off] =
        *(const short8*)&sh[row * 32 + off];
    __syncthreads();
  }
}

__global__ __launch_bounds__(256) void pack_wcat(
    const float* __restrict__ Wfg, const float* __restrict__ Wbg,
    u16* __restrict__ Wcat)
{
  const int idx = blockIdx.x * 256 + threadIdx.x;
  if (idx >= 72 * 512) return;
  const int o = idx >> 9, c = idx & 511;
  const float v = (c < 256) ? Wfg[o * 256 + c] : -Wbg[o * 256 + (c - 256)];
  Wcat[idx] = f2bf(v);
}

__global__ __launch_bounds__(256) void attn_gemm(
    const u16* __restrict__ G, const u16* __restrict__ Wcat,
    const float* __restrict__ bfg, const float* __restrict__ bbg,
    float* __restrict__ Lg)
{
  __shared__ u16 smem[4096];

  const int tid  = threadIdx.x;
  const int lane = tid & 63;
  const int wid  = tid >> 6;
  const int pix0 = blockIdx.x * 128;

  const int ch8 = (tid & 3) * 8;
  int aoff[2];
  #pragma unroll
  for (int i = 0; i < 2; ++i){
    const int row = (tid + i * 256) >> 2;
    aoff[i] = (pix0 + row) * 512 + ch8;
  }

  u16* ldsA0 = (u16*)((char*)smem + 0    + wid * 1024);
  u16* ldsA1 = (u16*)((char*)smem + 4096 + wid * 1024);

  f32x4 acc[2][5];
  #pragma unroll
  for (int m = 0; m < 2; ++m)
    #pragma unroll
    for (int n = 0; n < 5; ++n)
      acc[m][n] = (f32x4){0.f, 0.f, 0.f, 0.f};

  const int fr = lane & 15;
  const int fc = (lane >> 4) * 8;

  for (int ks = 0; ks < 16; ++ks){
    const int kb = ks * 32;
    __syncthreads();
    gll16(G + aoff[0] + kb, ldsA0);
    gll16(G + aoff[1] + kb, ldsA1);
    __syncthreads();

    short8 a[2];
    #pragma unroll
    for (int m = 0; m < 2; ++m)
      a[m] = *(const short8*)&smem[(wid * 32 + m * 16 + fr) * 32 + fc];
    #pragma unroll
    for (int n = 0; n < 5; ++n){
      short8 bfrag = *(const short8*)&Wcat[(size_t)(n * 16 + fr) * 512 + kb + fc];
      #pragma unroll
      for (int m = 0; m < 2; ++m)
        acc[m][n] = __builtin_amdgcn_mfma_f32_16x16x32_bf16(a[m], bfrag, acc[m][n], 0, 0, 0);
    }
  }

  #pragma unroll
  for (int n = 0; n < 5; ++n){
    const int col = n * 16 + fr;
    if (col >= 72) continue;
    const float bias = bfg[col] - bbg[col];
    #pragma unroll
    for (int m = 0; m < 2; ++m)
      #pragma unroll
      for (int r = 0; r < 4; ++r){
        const int pix = pix0 + wid * 32 + m * 16 + (lane >> 4) * 4 + r;
        Lg[(size_t)pix * 72 + col] = acc[m][n][r] + bias;
      }
  }
}

__global__ __launch_bounds__(256) void softmax_kernel(
    const float* __restrict__ Lg, float* __restrict__ attn)
{
  const int p  = blockIdx.x * 256 + threadIdx.x;
  const int b  = p >> 12;
  const int yx = p & 4095;

  float d[72];
  #pragma unroll
  for (int i = 0; i < 18; ++i)
    *(float4*)&d[i * 4] = *(const float4*)&Lg[(size_t)p * 72 + i * 4];

  #pragma unroll
  for (int h = 0; h < HEADS; ++h){
    float l[KK];
    #pragma unroll
    for (int k = 0; k < KK; ++k) l[k] = d[h * KK + k] * kInvSqrtD;
    float mx = l[0];
    #pragma unroll
    for (int k = 1; k < KK; ++k) mx = fmaxf(mx, l[k]);
    float e[KK], sum = 0.f;
    #pragma unroll
    for (int k = 0; k < KK; ++k){ e[k] = __expf(l[k] - mx); sum += e[k]; }
    const float inv = 1.f / sum;
    #pragma unroll
    for (int k = 0; k < KK; ++k)
      attn[(((size_t)b * HEADS + h) * KK + k) * HW + yx] = e[k] * inv;
  }
}

__global__ __launch_bounds__(256) void fold_sum_kernel(
    const float* __restrict__ attn, float* __restrict__ S)
{
  const int idx = blockIdx.x * 256 + threadIdx.x;
  const int bh  = idx >> 12;
  const int yx  = idx & 4095;
  const int y   = yx >> 6;
  const int x   = yx & 63;

  const float* ap = attn + (size_t)bh * KK * HW;
  float s = 0.f;
  #pragma unroll
  for (int i = 0; i < 3; ++i){
    const int ys = y + 1 - i;
    if (ys < 0 || ys >= H_) continue;
    #pragma unroll
    for (int j = 0; j < 3; ++j){
      const int xs = x + 1 - j;
      if (xs < 0 || xs >= W_) continue;
      s += ap[(size_t)(i * 3 + j) * HW + ys * W_ + xs];
    }
  }
  S[idx] = s;
}

// ---------------------------------------------------------------------------
extern "C" void kernel_launch(void* const* d_in, const int* in_sizes, int n_in,
                              void* d_out, int out_size, void* d_ws, size_t ws_size,
                              hipStream_t stream)
{
  const float* x   = (const float*)d_in[0];
  const float* fg  = (const float*)d_in[1];
  const float* bg  = (const float*)d_in[2];
  const float* w1  = (const float*)d_in[3];
  const float* g1  = (const float*)d_in[4];
  const float* b1  = (const float*)d_in[5];
  const float* m1  = (const float*)d_in[6];
  const float* v1  = (const float*)d_in[7];
  const float* w2  = (const float*)d_in[8];
  const float* g2  = (const float*)d_in[9];
  const float* b2  = (const float*)d_in[10];
  const float* m2  = (const float*)d_in[11];
  const float* v2  = (const float*)d_in[12];
  const float* Wv  = (const float*)d_in[13];
  const float* bv  = (const float*)d_in[14];
  const float* Wfg = (const float*)d_in[15];
  const float* bfg = (const float*)d_in[16];
  const float* Wbg = (const float*)d_in[17];
  const float* bbg = (const float*)d_in[18];
  const float* Wp  = (const float*)d_in[19];
  const float* bp  = (const float*)d_in[20];
  const float* w3  = (const float*)d_in[21];
  const float* g3  = (const float*)d_in[22];
  const float* b3  = (const float*)d_in[23];
  const float* m3  = (const float*)d_in[24];
  const float* v3  = (const float*)d_in[25];
  const float* w4  = (const float*)d_in[26];
  const float* g4  = (const float*)d_in[27];
  const float* b4  = (const float*)d_in[28];
  const float* m4  = (const float*)d_in[29];
  const float* v4  = (const float*)d_in[30];

  const size_t XB = (size_t)BATCH * PADR * 64 * 2;    // 4,460,544
  const size_t PB = (size_t)BATCH * PADR * 256 * 2;   // 17,842,176

  char* p = (char*)d_ws;
  u16* xpad = (u16*)p;             p += XB;
  u16* slA  = (u16*)p;             p += PB;
  u16* slB  = (u16*)p;             p += PB;   // adjacent to slA (G spans both)
  u16* w1f = (u16*)p; p += 294912;
  u16* w2f = (u16*)p; p += 1179648;
  u16* w3f = (u16*)p; p += 1179648;
  u16* w4f = (u16*)p; p += 1179648;
  u16* wvf = (u16*)p; p += 131072;
  u16* wpf = (u16*)p; p += 131072;
  u16* wcat = (u16*)p;             p += 80 * 512 * 2;
  float* attn = (float*)p;         p += (size_t)BATCH * HEADS * KK * HW * 4;
  float* S    = (float*)p;         p += (size_t)BATCH * HEADS * HW * 4;
  float* Lg   = (float*)p;         p += (size_t)BATCH * HW * 72 * 4;

  // attn temporaries: G (33.55 MB) aliases slA+slB (35.68 MB), dead after fold
  u16* G = slA;

  const dim3 blk(256);
  const int PIX_BLOCKS = (BATCH * HW) / 256;   // 128

  // ---- weight/input packs ----
  hipMemsetAsync(xpad, 0, XB, stream);
  hipMemsetAsync(wcat, 0, 80 * 512 * 2, stream);
  pack_w_f16<<<dim3((147456 + 255) / 256), blk, 0, stream>>>(w1, w1f, 64, 9, 147456);
  pack_w_f16<<<dim3((589824 + 255) / 256), blk, 0, stream>>>(w2, w2f, 256, 9, 589824);
  pack_w_f16<<<dim3((589824 + 255) / 256), blk, 0, stream>>>(w3, w3f, 256, 9, 589824);
  pack_w_f16<<<dim3((589824 + 255) / 256), blk, 0, stream>>>(w4, w4f, 256, 9, 589824);
  pack_w_f16<<<dim3((65536 + 255) / 256), blk, 0, stream>>>(Wv, wvf, 256, 1, 65536);
  pack_w_f16<<<dim3((65536 + 255) / 256), blk, 0, stream>>>(Wp, wpf, 256, 1, 65536);
  pack_wcat<<<dim3(144), blk, 0, stream>>>(Wfg, Wbg, wcat);
  pack_x64<<<dim3(PIX_BLOCKS), blk, 0, stream>>>(x, xpad);

  // ---- attention path (G over slA/slB, before conv-slot memsets) ----
  pack_fgbg<<<dim3((BATCH * HW) / 64), blk, 0, stream>>>(fg, bg, G);
  attn_gemm<<<dim3((BATCH * HW) / 128), blk, 0, stream>>>(G, wcat, bfg, bbg, Lg);
  softmax_kernel<<<dim3(PIX_BLOCKS), blk, 0, stream>>>(Lg, attn);
  fold_sum_kernel<<<dim3((BATCH * HEADS * HW) / 256), blk, 0, stream>>>(attn, S);

  // ---- zero conv slots (borders must be 0; kills G) ----
  hipMemsetAsync(slA, 0, PB, stream);
  hipMemsetAsync(slB, 0, PB, stream);

  const dim3 ggrid(256, 2);
  // conv1: xpad -> slA (h1)
  gemm_conv<64, 9, 0><<<ggrid, blk, 0, stream>>>(
      xpad, w1f, g1, b1, m1, v1, nullptr, slA, nullptr);
  // conv2: slA -> slB (h2)
  gemm_conv<256, 9, 0><<<ggrid, blk, 0, stream>>>(
      slA, w2f, g2, b2, m2, v2, nullptr, slB, nullptr);
  // Wv + S-mul: slB -> slA (v*S)
  gemm_conv<256, 1, 1><<<ggrid, blk, 0, stream>>>(
      slB, wvf, bv, nullptr, nullptr, nullptr, S, slA, nullptr);
  // Wp: slA -> slB (o)
  gemm_conv<256, 1, 2><<<ggrid, blk, 0, stream>>>(
      slA, wpf, bp, nullptr, nullptr, nullptr, nullptr, slB, nullptr);
  // conv3: slB -> slA (h3)
  gemm_conv<256, 9, 0><<<ggrid, blk, 0, stream>>>(
      slB, w3f, g3, b3, m3, v3, nullptr, slA, nullptr);
  // conv4: slA -> d_out (f32 channel-major)
  gemm_conv<256, 9, 3><<<ggrid, blk, 0, stream>>>(
      slA, w4f, g4, b4, m4, v4, nullptr, nullptr, (float*)d_out);
}

// Round 5
// 269.543 us; speedup vs baseline: 11.4314x; 1.0379x over previous
//
#include <hip/hip_runtime.h>
#include <cstddef>

#define BATCH 8
#define H_ 64
#define W_ 64
#define HW 4096
#define DIM 256
#define HEADS 8
#define KK 9
#define PADR 4356   // 66*66 padded pixels per batch

typedef unsigned short u16;
typedef unsigned int u32;
typedef __attribute__((ext_vector_type(8))) short short8;      // 8 bf16
typedef _Float16 __attribute__((ext_vector_type(8))) h8;       // 8 f16
typedef __attribute__((ext_vector_type(4))) float f32x4;

constexpr float kEps = 1e-5f;
constexpr float kInvSqrtD = 0.17677669529663687f;  // 32^-0.5

__device__ __forceinline__ u16 f2bf(float f){
  u32 u = __float_as_uint(f);
  u = (u + 0x7fffu + ((u >> 16) & 1u)) >> 16;
  return (u16)u;
}
__device__ __forceinline__ u16 f2h(float f){
  union { _Float16 h; u16 u; } cv;
  cv.h = (_Float16)f;                  // RNE f32->f16
  return cv.u;
}

__device__ __forceinline__ void gll16(const u16* g, u16* lds){
  __builtin_amdgcn_global_load_lds((const __attribute__((address_space(1))) u32*)g,
                                   (__attribute__((address_space(3))) u32*)lds, 16, 0, 0);
}

// ---------------------------------------------------------------------------
// Implicit-GEMM conv, plain f16 MFMA (verified round 4).
// Tile: BM=128 px x BN=128 oc, BK=64; 4 waves; 64KB LDS double-buffer;
// XOR-swizzled LDS via pre-swizzled global source; 2-phase prefetch pipeline.
// ---------------------------------------------------------------------------
template<int CIN, int NTAP, int EPI>
__global__ __launch_bounds__(256, 2) void gemm_conv(
    const u16* __restrict__ Act, const u16* __restrict__ Wt,
    const float* __restrict__ q0, const float* __restrict__ q1,
    const float* __restrict__ q2, const float* __restrict__ q3,
    const float* __restrict__ Smap,
    u16* __restrict__ Opad, float* __restrict__ Of32)
{
  constexpr int KCH = CIN / 64;
  constexpr int KSTEPS = NTAP * KCH;
  __shared__ u16 smem[32768];

  const int tid  = threadIdx.x;
  const int lane = tid & 63;
  const int wid  = tid >> 6;
  const int wm   = wid >> 1, wn = wid & 1;
  const int fr   = lane & 15;
  const int g    = lane >> 4;
  const int pix0 = blockIdx.x * 128;
  const int oc0  = blockIdx.y * 128;

  const int csw = ((tid & 7) ^ ((tid >> 3) & 7)) << 3;
  int a_src[4], b_src[4];
  #pragma unroll
  for (int q = 0; q < 4; ++q){
    const int r = q * 32 + (tid >> 3);
    const int pix = pix0 + r;
    const int b = pix >> 12, yx = pix & 4095;
    const int y = yx >> 6, x = yx & 63;
    a_src[q] = (b * PADR + (y + 1) * 66 + (x + 1)) * CIN + csw;
    b_src[q] = (oc0 + r) * CIN + csw;
  }

  f32x4 acc[4][4];
  #pragma unroll
  for (int m = 0; m < 4; ++m)
    #pragma unroll
    for (int n = 0; n < 4; ++n)
      acc[m][n] = (f32x4){0.f, 0.f, 0.f, 0.f};

  auto stage = [&](int ks, int bsel){
    const int t  = (KCH == 1) ? ks : (ks / KCH);
    const int kb = (KCH == 1) ? 0  : ((ks % KCH) << 6);
    int ao = kb;
    if constexpr (NTAP == 9) ao += ((t / 3 - 1) * 66 + (t % 3 - 1)) * CIN;
    const int bo = t * (256 * CIN) + kb;
    u16* lA = smem + bsel * 16384 + wid * 512;
    u16* lB = lA + 8192;
    #pragma unroll
    for (int q = 0; q < 4; ++q){
      gll16(Act + a_src[q] + ao, lA + q * 2048);
      gll16(Wt  + b_src[q] + bo, lB + q * 2048);
    }
  };

  stage(0, 0);
  __syncthreads();

  for (int ks = 0; ks < KSTEPS; ++ks){
    const int bsel = ks & 1;
    if (ks + 1 < KSTEPS) stage(ks + 1, bsel ^ 1);

    const u16* base = smem + bsel * 16384;
    h8 a[4][2], bb[4][2];
    #pragma unroll
    for (int m = 0; m < 4; ++m){
      const int R = wm * 64 + m * 16 + fr;
      #pragma unroll
      for (int kk = 0; kk < 2; ++kk)
        a[m][kk] = *(const h8*)&base[R * 64 + ((((kk << 2) + g) ^ (fr & 7)) << 3)];
    }
    #pragma unroll
    for (int n = 0; n < 4; ++n){
      const int R = wn * 64 + n * 16 + fr;
      #pragma unroll
      for (int kk = 0; kk < 2; ++kk)
        bb[n][kk] = *(const h8*)&base[8192 + R * 64 + ((((kk << 2) + g) ^ (fr & 7)) << 3)];
    }
    #pragma unroll
    for (int kk = 0; kk < 2; ++kk)
      #pragma unroll
      for (int n = 0; n < 4; ++n)
        #pragma unroll
        for (int m = 0; m < 4; ++m)
          acc[m][n] = __builtin_amdgcn_mfma_f32_16x16x32_f16(a[m][kk], bb[n][kk], acc[m][n], 0, 0, 0);

    __syncthreads();
  }

  #pragma unroll
  for (int n = 0; n < 4; ++n){
    const int oc = oc0 + wn * 64 + n * 16 + fr;
    float sc, shv;
    if constexpr (EPI == 0 || EPI == 3){
      sc  = q0[oc] * rsqrtf(q3[oc] + kEps);
      shv = q1[oc] - q2[oc] * sc;
    } else {
      sc = 1.f; shv = q0[oc];
      (void)q1; (void)q2; (void)q3;
    }
    #pragma unroll
    for (int m = 0; m < 4; ++m){
      const int pixb = pix0 + wm * 64 + m * 16 + g * 4;
      f32x4 aa = acc[m][n];
      if constexpr (EPI == 3){
        const int b = pixb >> 12, yx = pixb & 4095;
        float4 o4;
        o4.x = fmaxf(fmaf(aa[0], sc, shv), 0.f);
        o4.y = fmaxf(fmaf(aa[1], sc, shv), 0.f);
        o4.z = fmaxf(fmaf(aa[2], sc, shv), 0.f);
        o4.w = fmaxf(fmaf(aa[3], sc, shv), 0.f);
        *(float4*)&Of32[((size_t)b * 256 + oc) * HW + yx] = o4;
      } else {
        #pragma unroll
        for (int r = 0; r < 4; ++r){
          const int pix = pixb + r;
          const int b = pix >> 12, yx = pix & 4095;
          const int y = yx >> 6, x = yx & 63;
          float v;
          if constexpr (EPI == 0)
            v = fmaxf(fmaf(aa[r], sc, shv), 0.f);
          else if constexpr (EPI == 1)
            v = (aa[r] + shv) * Smap[((size_t)b * HEADS + (oc >> 5)) * HW + yx];
          else
            v = aa[r] + shv;
          Opad[((size_t)b * PADR + (y + 1) * 66 + (x + 1)) * 256 + oc] = f2h(v);
        }
      }
    }
  }
}

// ---------------------------------------------------------------------------
// Weight pack: w flat [O=256][C][T] f32 -> f16 [T][256][C]
// ---------------------------------------------------------------------------
__global__ __launch_bounds__(256) void pack_w_f16(const float* __restrict__ w,
    u16* __restrict__ dst, int C, int T, int N)
{
  const int idx = blockIdx.x * 256 + threadIdx.x;
  if (idx >= N) return;
  const int o = idx / (C * T);
  const int rem = idx - o * C * T;
  const int c = rem / T;
  const int t = rem - c * T;
  dst[((size_t)t * 256 + o) * C + c] = f2h(w[idx]);
}

// ---------------------------------------------------------------------------
// Input pack: x f32 [8][64][4096] -> padded pixel-major f16 [8][4356][64]
// ---------------------------------------------------------------------------
__global__ __launch_bounds__(256) void pack_x64(const float* __restrict__ x,
    u16* __restrict__ xp)
{
  const int p = blockIdx.x * 256 + threadIdx.x;
  const int b = p >> 12, yx = p & 4095;
  const int y = yx >> 6, xx = yx & 63;
  const size_t pr = ((size_t)b * PADR + (y + 1) * 66 + (xx + 1)) * 64;
  const float* xs = x + (size_t)b * 64 * HW + yx;
  #pragma unroll 8
  for (int c = 0; c < 64; c += 2){
    const u16 h0 = f2h(xs[(size_t)c * HW]);
    const u16 h1 = f2h(xs[(size_t)(c + 1) * HW]);
    *(u32*)&xp[pr + c] = (u32)h0 | ((u32)h1 << 16);
  }
}

// ---------------------------------------------------------------------------
// pack fg,bg -> G[32768][512] bf16 pixel-major. NO LDS: thread = 2px x 32ch.
// Reads: float2, 64 consecutive lanes per channel (512B/instr coalesced).
// Writes: 64B contiguous bf16 per pixel-row per thread.
// ---------------------------------------------------------------------------
__global__ __launch_bounds__(256) void pack_fgbg(
    const float* __restrict__ fg, const float* __restrict__ bg,
    u16* __restrict__ G)
{
  const int t = threadIdx.x;
  const int pix0 = blockIdx.x * 128;          // 256 x-blocks
  const int chg  = blockIdx.y * 128 + (t >> 6) * 32;   // 4 y-blocks
  const int pix  = pix0 + (t & 63) * 2;
  const int b = pix >> 12, yx = pix & 4095;

  u16 buf0[32], buf1[32];
  #pragma unroll
  for (int i = 0; i < 32; ++i){
    const int c = chg + i;
    const float* src = (c < 256)
        ? &fg[((size_t)b * 256 + c) * HW + yx]
        : &bg[((size_t)b * 256 + (c - 256)) * HW + yx];
    const float2 v = *(const float2*)src;
    buf0[i] = f2bf(v.x);
    buf1[i] = f2bf(v.y);
  }
  #pragma unroll
  for (int i = 0; i < 32; i += 8)
    *(short8*)&G[(size_t)pix * 512 + chg + i] = *(short8*)&buf0[i];
  #pragma unroll
  for (int i = 0; i < 32; i += 8)
    *(short8*)&G[(size_t)(pix + 1) * 512 + chg + i] = *(short8*)&buf1[i];
}

__global__ __launch_bounds__(256) void pack_wcat(
    const float* __restrict__ Wfg, const float* __restrict__ Wbg,
    u16* __restrict__ Wcat)
{
  const int idx = blockIdx.x * 256 + threadIdx.x;
  if (idx >= 72 * 512) return;
  const int o = idx >> 9, c = idx & 511;
  const float v = (c < 256) ? Wfg[o * 256 + c] : -Wbg[o * 256 + (c - 256)];
  Wcat[idx] = f2bf(v);
}

// ---------------------------------------------------------------------------
// attn logits GEMM with 2-phase prefetch: Lg[32768][72] = G @ Wcat^T + bias
// ---------------------------------------------------------------------------
__global__ __launch_bounds__(256) void attn_gemm(
    const u16* __restrict__ G, const u16* __restrict__ Wcat,
    const float* __restrict__ bfg, const float* __restrict__ bbg,
    float* __restrict__ Lg)
{
  __shared__ u16 smem[8192];   // 2 x (128 rows x 32 ch)

  const int tid  = threadIdx.x;
  const int lane = tid & 63;
  const int wid  = tid >> 6;
  const int pix0 = blockIdx.x * 128;

  const int ch8 = (tid & 3) * 8;
  int aoff[2];
  #pragma unroll
  for (int i = 0; i < 2; ++i){
    const int row = (tid + i * 256) >> 2;
    aoff[i] = (pix0 + row) * 512 + ch8;
  }

  f32x4 acc[2][5];
  #pragma unroll
  for (int m = 0; m < 2; ++m)
    #pragma unroll
    for (int n = 0; n < 5; ++n)
      acc[m][n] = (f32x4){0.f, 0.f, 0.f, 0.f};

  const int fr = lane & 15;
  const int fc = (lane >> 4) * 8;

  auto stage = [&](int ks, int bsel){
    u16* lA = smem + bsel * 4096 + wid * 512;
    gll16(G + aoff[0] + ks * 32, lA);
    gll16(G + aoff[1] + ks * 32, lA + 2048);
  };

  stage(0, 0);
  __syncthreads();

  for (int ks = 0; ks < 16; ++ks){
    const int bsel = ks & 1;
    if (ks + 1 < 16) stage(ks + 1, bsel ^ 1);

    const u16* base = smem + bsel * 4096;
    short8 a[2];
    #pragma unroll
    for (int m = 0; m < 2; ++m)
      a[m] = *(const short8*)&base[(wid * 32 + m * 16 + fr) * 32 + fc];
    #pragma unroll
    for (int n = 0; n < 5; ++n){
      short8 bfrag = *(const short8*)&Wcat[(size_t)(n * 16 + fr) * 512 + ks * 32 + fc];
      #pragma unroll
      for (int m = 0; m < 2; ++m)
        acc[m][n] = __builtin_amdgcn_mfma_f32_16x16x32_bf16(a[m], bfrag, acc[m][n], 0, 0, 0);
    }
    __syncthreads();
  }

  #pragma unroll
  for (int n = 0; n < 5; ++n){
    const int col = n * 16 + fr;
    if (col >= 72) continue;
    const float bias = bfg[col] - bbg[col];
    #pragma unroll
    for (int m = 0; m < 2; ++m)
      #pragma unroll
      for (int r = 0; r < 4; ++r){
        const int pix = pix0 + wid * 32 + m * 16 + (lane >> 4) * 4 + r;
        Lg[(size_t)pix * 72 + col] = acc[m][n][r] + bias;
      }
  }
}

// ---------------------------------------------------------------------------
// Fused softmax+fold: S[b,h,y,x] = sum_{i,j valid} softmax(Lg[nbr])[h,3i+j]
// where nbr=(y+1-i, x+1-j). Thread = pixel; Lg is L2-resident.
// ---------------------------------------------------------------------------
__global__ __launch_bounds__(256) void softmax_fold(
    const float* __restrict__ Lg, float* __restrict__ S)
{
  const int p  = blockIdx.x * 256 + threadIdx.x;
  const int b  = p >> 12;
  const int yx = p & 4095;
  const int y  = yx >> 6, x = yx & 63;

  float s[8];
  #pragma unroll
  for (int h = 0; h < 8; ++h) s[h] = 0.f;

  #pragma unroll
  for (int i = 0; i < 3; ++i){
    const int ys = y + 1 - i;
    if (ys < 0 || ys >= H_) continue;
    #pragma unroll
    for (int j = 0; j < 3; ++j){
      const int xs = x + 1 - j;
      if (xs < 0 || xs >= W_) continue;
      const int pn = (b << 12) + ys * W_ + xs;
      const int k  = i * 3 + j;
      float d[72];
      #pragma unroll
      for (int q = 0; q < 18; ++q)
        *(float4*)&d[q * 4] = *(const float4*)&Lg[(size_t)pn * 72 + q * 4];
      #pragma unroll
      for (int h = 0; h < 8; ++h){
        float mx = d[h * 9];
        #pragma unroll
        for (int kk = 1; kk < 9; ++kk) mx = fmaxf(mx, d[h * 9 + kk]);
        float e[9], sum = 0.f;
        #pragma unroll
        for (int kk = 0; kk < 9; ++kk){
          e[kk] = __expf((d[h * 9 + kk] - mx) * kInvSqrtD);
          sum += e[kk];
        }
        s[h] += e[k] / sum;
      }
    }
  }
  #pragma unroll
  for (int h = 0; h < 8; ++h)
    S[(((size_t)b * HEADS + h) << 12) + yx] = s[h];
}

// ---------------------------------------------------------------------------
extern "C" void kernel_launch(void* const* d_in, const int* in_sizes, int n_in,
                              void* d_out, int out_size, void* d_ws, size_t ws_size,
                              hipStream_t stream)
{
  const float* x   = (const float*)d_in[0];
  const float* fg  = (const float*)d_in[1];
  const float* bg  = (const float*)d_in[2];
  const float* w1  = (const float*)d_in[3];
  const float* g1  = (const float*)d_in[4];
  const float* b1  = (const float*)d_in[5];
  const float* m1  = (const float*)d_in[6];
  const float* v1  = (const float*)d_in[7];
  const float* w2  = (const float*)d_in[8];
  const float* g2  = (const float*)d_in[9];
  const float* b2  = (const float*)d_in[10];
  const float* m2  = (const float*)d_in[11];
  const float* v2  = (const float*)d_in[12];
  const float* Wv  = (const float*)d_in[13];
  const float* bv  = (const float*)d_in[14];
  const float* Wfg = (const float*)d_in[15];
  const float* bfg = (const float*)d_in[16];
  const float* Wbg = (const float*)d_in[17];
  const float* bbg = (const float*)d_in[18];
  const float* Wp  = (const float*)d_in[19];
  const float* bp  = (const float*)d_in[20];
  const float* w3  = (const float*)d_in[21];
  const float* g3  = (const float*)d_in[22];
  const float* b3  = (const float*)d_in[23];
  const float* m3  = (const float*)d_in[24];
  const float* v3  = (const float*)d_in[25];
  const float* w4  = (const float*)d_in[26];
  const float* g4  = (const float*)d_in[27];
  const float* b4  = (const float*)d_in[28];
  const float* m4  = (const float*)d_in[29];
  const float* v4  = (const float*)d_in[30];

  const size_t XB = (size_t)BATCH * PADR * 64 * 2;    // 4,460,544
  const size_t PB = (size_t)BATCH * PADR * 256 * 2;   // 17,842,176

  char* p = (char*)d_ws;
  u16* xpad = (u16*)p;             p += XB;
  u16* slA  = (u16*)p;             p += PB;
  u16* slB  = (u16*)p;             p += PB;   // adjacent to slA (G spans both)
  u16* w1f = (u16*)p; p += 294912;
  u16* w2f = (u16*)p; p += 1179648;
  u16* w3f = (u16*)p; p += 1179648;
  u16* w4f = (u16*)p; p += 1179648;
  u16* wvf = (u16*)p; p += 131072;
  u16* wpf = (u16*)p; p += 131072;
  u16* wcat = (u16*)p;             p += 80 * 512 * 2;
  float* S    = (float*)p;         p += (size_t)BATCH * HEADS * HW * 4;
  float* Lg   = (float*)p;         p += (size_t)BATCH * HW * 72 * 4;

  // attn temporary: G (33.55 MB) aliases slA+slB (35.68 MB), dead after fold
  u16* G = slA;

  const dim3 blk(256);
  const int PIX_BLOCKS = (BATCH * HW) / 256;   // 128

  // ---- weight/input packs ----
  hipMemsetAsync(xpad, 0, XB, stream);
  hipMemsetAsync(wcat, 0, 80 * 512 * 2, stream);
  pack_w_f16<<<dim3((147456 + 255) / 256), blk, 0, stream>>>(w1, w1f, 64, 9, 147456);
  pack_w_f16<<<dim3((589824 + 255) / 256), blk, 0, stream>>>(w2, w2f, 256, 9, 589824);
  pack_w_f16<<<dim3((589824 + 255) / 256), blk, 0, stream>>>(w3, w3f, 256, 9, 589824);
  pack_w_f16<<<dim3((589824 + 255) / 256), blk, 0, stream>>>(w4, w4f, 256, 9, 589824);
  pack_w_f16<<<dim3((65536 + 255) / 256), blk, 0, stream>>>(Wv, wvf, 256, 1, 65536);
  pack_w_f16<<<dim3((65536 + 255) / 256), blk, 0, stream>>>(Wp, wpf, 256, 1, 65536);
  pack_wcat<<<dim3(144), blk, 0, stream>>>(Wfg, Wbg, wcat);
  pack_x64<<<dim3(PIX_BLOCKS), blk, 0, stream>>>(x, xpad);

  // ---- attention path (G over slA/slB, before conv-slot memsets) ----
  pack_fgbg<<<dim3(256, 4), blk, 0, stream>>>(fg, bg, G);
  attn_gemm<<<dim3((BATCH * HW) / 128), blk, 0, stream>>>(G, wcat, bfg, bbg, Lg);
  softmax_fold<<<dim3(PIX_BLOCKS), blk, 0, stream>>>(Lg, S);

  // ---- zero conv slots (borders must be 0; kills G) ----
  hipMemsetAsync(slA, 0, PB, stream);
  hipMemsetAsync(slB, 0, PB, stream);

  const dim3 ggrid(256, 2);
  // conv1: xpad -> slA (h1)
  gemm_conv<64, 9, 0><<<ggrid, blk, 0, stream>>>(
      xpad, w1f, g1, b1, m1, v1, nullptr, slA, nullptr);
  // conv2: slA -> slB (h2)
  gemm_conv<256, 9, 0><<<ggrid, blk, 0, stream>>>(
      slA, w2f, g2, b2, m2, v2, nullptr, slB, nullptr);
  // Wv + S-mul: slB -> slA (v*S)
  gemm_conv<256, 1, 1><<<ggrid, blk, 0, stream>>>(
      slB, wvf, bv, nullptr, nullptr, nullptr, S, slA, nullptr);
  // Wp: slA -> slB (o)
  gemm_conv<256, 1, 2><<<ggrid, blk, 0, stream>>>(
      slA, wpf, bp, nullptr, nullptr, nullptr, nullptr, slB, nullptr);
  // conv3: slB -> slA (h3)
  gemm_conv<256, 9, 0><<<ggrid, blk, 0, stream>>>(
      slB, w3f, g3, b3, m3, v3, nullptr, slA, nullptr);
  // conv4: slA -> d_out (f32 channel-major)
  gemm_conv<256, 9, 3><<<ggrid, blk, 0, stream>>>(
      slA, w4f, g4, b4, m4, v4, nullptr, nullptr, (float*)d_out);
}